// Round 12
// baseline (341.835 us; speedup 1.0000x reference)
//
#include <hip/hip_runtime.h>

constexpr int DFEAT  = 64;
constexpr int KSTEPS = 10;
constexpr float ALPHA = 0.1f;
constexpr int PAD    = 8;       // CSR row length padded to multiple of 8
constexpr int BSHIFT = 8;       // 256 nodes per dst bucket
constexpr int MAXBUCK = 512;    // max buckets (N <= 131072)
constexpr int GR_A   = 128;     // bucketing blocks
constexpr int SRCSHIFT = 14;    // src-range = 16384 nodes (~2MB bf16 window)

constexpr int SCAN_T    = 256;
constexpr int SCAN_I    = 4;
constexpr int SCAN_TILE = SCAN_T * SCAN_I;  // 1024

typedef unsigned int u32;
typedef __attribute__((ext_vector_type(4))) unsigned int u32x4;

// bf16 pack helper (round-to-nearest-even), returns low 16 bits
__device__ inline u32 f2bf(float f) {
    u32 u = __float_as_uint(f);
    return ((u + 0x7fffu + ((u >> 16) & 1u)) >> 16) & 0xFFFFu;
}
__device__ inline float bfLO(u32 v) { return __uint_as_float(v << 16); }
__device__ inline float bfHI(u32 v) { return __uint_as_float(v & 0xFFFF0000u); }

// ---- A1 (fused): blocks [0,GR_A): LDS bucket histogram; rest: x->bf16 cvt ----
__global__ void __launch_bounds__(256) k_hA_cvt(
    const int* __restrict__ col, int* __restrict__ blockhist,
    int E, int nb, int chunk,
    const float* __restrict__ x, u32* __restrict__ xb, int n8) {
    __shared__ int hist[MAXBUCK];
    int t = threadIdx.x;
    if ((int)blockIdx.x < GR_A) {
        int e0 = blockIdx.x * chunk;
        int e1 = min(E, e0 + chunk);
        for (int b = t; b < MAXBUCK; b += 256) hist[b] = 0;
        __syncthreads();
        for (int e = e0 + t; e < e1; e += 256)
            atomicAdd(&hist[col[e] >> BSHIFT], 1);
        __syncthreads();
        for (int b = t; b < nb; b += 256)
            blockhist[blockIdx.x * MAXBUCK + b] = hist[b];
    } else {
        int stride = (gridDim.x - GR_A) * blockDim.x;
        const float4* x4 = (const float4*)x;
        u32x4* o4 = (u32x4*)xb;
        for (int i = (blockIdx.x - GR_A) * blockDim.x + t; i < n8; i += stride) {
            float4 a = x4[2 * i], b = x4[2 * i + 1];
            u32x4 o;
            o.x = (f2bf(a.y) << 16) | f2bf(a.x);
            o.y = (f2bf(a.w) << 16) | f2bf(a.z);
            o.z = (f2bf(b.y) << 16) | f2bf(b.x);
            o.w = (f2bf(b.w) << 16) | f2bf(b.z);
            o4[i] = o;
        }
    }
}

// ---- A2: per bucket, exclusive scan over the GR_A per-block counts ----
__global__ void k_colsum(int* __restrict__ blockhist, int* __restrict__ btotal) {
    __shared__ int s[GR_A];
    int b = blockIdx.x, t = threadIdx.x;     // GR_A threads
    int v = blockhist[t * MAXBUCK + b];
    s[t] = v;
    __syncthreads();
    for (int o = 1; o < GR_A; o <<= 1) {
        int u = (t >= o) ? s[t - o] : 0;
        __syncthreads();
        s[t] += u;
        __syncthreads();
    }
    blockhist[t * MAXBUCK + b] = s[t] - v;   // exclusive
    if (t == GR_A - 1) btotal[b] = s[t];
}

// ---- A3: exclusive scan of bucket totals -> bstart ----
__global__ void k_bscan(const int* __restrict__ btotal, int* __restrict__ bstart,
                        int nb) {
    __shared__ int s[MAXBUCK];
    int t = threadIdx.x;
    if (t < nb) s[t] = btotal[t];
    __syncthreads();
    if (t == 0) {
        int acc = 0;
        for (int i = 0; i < nb; ++i) { int v = s[i]; s[i] = acc; acc += v; }
    }
    __syncthreads();
    if (t < nb) bstart[t] = s[t];
}

// ---- A4: write edges into pre-reserved bucket segments (LDS cursors only) ----
__global__ void __launch_bounds__(256) k_hB(
    const int* __restrict__ row, const int* __restrict__ col,
    const int* __restrict__ blockhist, const int* __restrict__ bstart,
    u32* __restrict__ bucketed, int E, int nb, int chunk) {
    __shared__ int cur[MAXBUCK];
    int t  = threadIdx.x;
    int e0 = blockIdx.x * chunk;
    int e1 = min(E, e0 + chunk);
    for (int b = t; b < nb; b += 256)
        cur[b] = bstart[b] + blockhist[blockIdx.x * MAXBUCK + b];
    __syncthreads();
    for (int e = e0 + t; e < e1; e += 256) {
        int c = col[e], r = row[e];
        int rank = atomicAdd(&cur[c >> BSHIFT], 1);
        bucketed[rank] = ((u32)r << BSHIFT) | (u32)(c & ((1 << BSHIFT) - 1));
    }
}

// ---- A5: per-bucket degree count from bucketed; emit dinv + dpad ----
__global__ void __launch_bounds__(256) k_degB(
    const u32* __restrict__ bucketed, const int* __restrict__ bstart,
    const int* __restrict__ btotal, float* __restrict__ dinv,
    int* __restrict__ dpad, int N) {
    __shared__ int cnt[256];
    int b = blockIdx.x, t = threadIdx.x;
    cnt[t] = 0;
    __syncthreads();
    int p0 = bstart[b], p1 = p0 + btotal[b];
    for (int p = p0 + t; p < p1; p += 256)
        atomicAdd(&cnt[bucketed[p] & 255u], 1);
    __syncthreads();
    int node = (b << BSHIFT) + t;
    if (node < N) {
        int d = cnt[t];
        dinv[node] = (d > 0) ? rsqrtf((float)d) : 0.0f;
        dpad[node] = (d + (PAD - 1)) & ~(PAD - 1);
    }
}

// ---- scan phase 1 (exclusive scan of dpad) ----
__global__ void k_scan1(const int* __restrict__ in, int* __restrict__ out,
                        int* __restrict__ bsum, int n) {
    __shared__ int s[SCAN_T];
    int tid  = threadIdx.x;
    int base = blockIdx.x * SCAN_TILE + tid * SCAN_I;
    int v[SCAN_I];
    int sum = 0;
#pragma unroll
    for (int j = 0; j < SCAN_I; ++j) {
        v[j] = (base + j < n) ? in[base + j] : 0;
        sum += v[j];
    }
    s[tid] = sum;
    __syncthreads();
    for (int ofs = 1; ofs < SCAN_T; ofs <<= 1) {
        int t = (tid >= ofs) ? s[tid - ofs] : 0;
        __syncthreads();
        s[tid] += t;
        __syncthreads();
    }
    int excl = (tid == 0) ? 0 : s[tid - 1];
    if (tid == SCAN_T - 1) bsum[blockIdx.x] = s[tid];
#pragma unroll
    for (int j = 0; j < SCAN_I; ++j) {
        if (base + j < n) out[base + j] = excl;
        excl += v[j];
    }
}

// ---- scan phase 3: offs += prefix of bsum (scan2 inlined per block) ----
__global__ void k_scan3(int* __restrict__ offs, const int* __restrict__ bsum, int n) {
    __shared__ int s_add;
    if (threadIdx.x == 0) {
        int acc = 0;
        for (int i = 0; i < (int)blockIdx.x; ++i) acc += bsum[i];
        s_add = acc;
    }
    __syncthreads();
    int add  = s_add;
    int base = blockIdx.x * SCAN_TILE + threadIdx.x * SCAN_I;
#pragma unroll
    for (int j = 0; j < SCAN_I; ++j) {
        int i = base + j;
        if (i < n) offs[i] += add;
    }
}

// ---- pass B: per-bucket CSR fill, SRC-RANGE-ORDERED rows ----
// Pass s appends only edges with src in range s -> each row's meta comes out
// sorted by src range. During k_prop all waves then walk src ranges in the
// same order, concentrating gathers into a ~2-4 MB sliding window that is
// L2-resident per XCD (read-only lines replicate cleanly).
__global__ void __launch_bounds__(256) k_fillB(
    const u32* __restrict__ bucketed, const int* __restrict__ bstart,
    const int* __restrict__ btotal, const int* __restrict__ offs,
    const float* __restrict__ dinv, u32* __restrict__ meta, int N) {
    __shared__ int   lcur[256];
    __shared__ float ldinv[256];
    int b = blockIdx.x, t = threadIdx.x;
    int node = (b << BSHIFT) + t;
    lcur[t]  = (node < N) ? offs[node] : 0;
    ldinv[t] = (node < N) ? dinv[node] : 0.0f;
    __syncthreads();
    int p0 = bstart[b], p1 = p0 + btotal[b];
    int nsrcr = (N + (1 << SRCSHIFT) - 1) >> SRCSHIFT;
    for (int s = 0; s < nsrcr; ++s) {
        for (int p = p0 + t; p < p1; p += 256) {
            u32 v  = bucketed[p];
            int r  = (int)(v >> BSHIFT);
            if ((r >> SRCSHIFT) != s) continue;
            int cl = (int)(v & 255u);
            int pos = atomicAdd(&lcur[cl], 1);
            float w = dinv[r] * ldinv[cl];            // in [0,1]
            u32 wq = (u32)__float2int_rn(w * 32768.0f);
            if (wq > 32767u) wq = 32767u;
            meta[pos] = (wq << 17) | (u32)r;
        }
        __syncthreads();   // keep range-s appends strictly before range-s+1
    }
}

// ---- propagate: one 8-lane group per dst node; lane l covers features l*8..l*8+7.
// PAD=8 rows -> uniform 8-deep MLP loop, double-buffered meta, no tail.
template<bool LAST>
__global__ void __launch_bounds__(256) k_prop(
    const int* __restrict__ offs, const int* __restrict__ dpad,
    const u32* __restrict__ meta, const u32* __restrict__ hsrc,
    const float* __restrict__ x, const u32* __restrict__ xb,
    void* __restrict__ hdst, int N) {
    int gid = (int)((blockIdx.x * blockDim.x + threadIdx.x) >> 3);  // node id
    int l   = threadIdx.x & 7;                                      // lane in group
    if (gid >= N) return;
    int j   = offs[gid];
    int end = j + dpad[gid];          // multiple of 8 (or 0)

    const u32x4* h4 = (const u32x4*)hsrc;   // row r = h4[r*8 .. r*8+7]
    float a0 = 0.f, a1 = 0.f, a2 = 0.f, a3 = 0.f,
          a4 = 0.f, a5 = 0.f, a6 = 0.f, a7 = 0.f;

    if (j < end) {
        u32x4 mA = *(const u32x4*)&meta[j];
        u32x4 mB = *(const u32x4*)&meta[j + 4];
        while (j < end) {
            int jn = j + 8;
            // 8 independent gathers in flight
            u32x4 q0 = h4[(size_t)(mA.x & 0x1FFFFu) * 8 + l];
            u32x4 q1 = h4[(size_t)(mA.y & 0x1FFFFu) * 8 + l];
            u32x4 q2 = h4[(size_t)(mA.z & 0x1FFFFu) * 8 + l];
            u32x4 q3 = h4[(size_t)(mA.w & 0x1FFFFu) * 8 + l];
            u32x4 q4 = h4[(size_t)(mB.x & 0x1FFFFu) * 8 + l];
            u32x4 q5 = h4[(size_t)(mB.y & 0x1FFFFu) * 8 + l];
            u32x4 q6 = h4[(size_t)(mB.z & 0x1FFFFu) * 8 + l];
            u32x4 q7 = h4[(size_t)(mB.w & 0x1FFFFu) * 8 + l];
            // prefetch next meta (slack-allocated past array end)
            u32x4 mA2 = *(const u32x4*)&meta[jn];
            u32x4 mB2 = *(const u32x4*)&meta[jn + 4];
            float w0 = (float)(mA.x >> 17) * (1.0f / 32768.0f);
            float w1 = (float)(mA.y >> 17) * (1.0f / 32768.0f);
            float w2 = (float)(mA.z >> 17) * (1.0f / 32768.0f);
            float w3 = (float)(mA.w >> 17) * (1.0f / 32768.0f);
            float w4 = (float)(mB.x >> 17) * (1.0f / 32768.0f);
            float w5 = (float)(mB.y >> 17) * (1.0f / 32768.0f);
            float w6 = (float)(mB.z >> 17) * (1.0f / 32768.0f);
            float w7 = (float)(mB.w >> 17) * (1.0f / 32768.0f);
            a0 += w0 * bfLO(q0.x); a1 += w0 * bfHI(q0.x);
            a2 += w0 * bfLO(q0.y); a3 += w0 * bfHI(q0.y);
            a4 += w0 * bfLO(q0.z); a5 += w0 * bfHI(q0.z);
            a6 += w0 * bfLO(q0.w); a7 += w0 * bfHI(q0.w);
            a0 += w1 * bfLO(q1.x); a1 += w1 * bfHI(q1.x);
            a2 += w1 * bfLO(q1.y); a3 += w1 * bfHI(q1.y);
            a4 += w1 * bfLO(q1.z); a5 += w1 * bfHI(q1.z);
            a6 += w1 * bfLO(q1.w); a7 += w1 * bfHI(q1.w);
            a0 += w2 * bfLO(q2.x); a1 += w2 * bfHI(q2.x);
            a2 += w2 * bfLO(q2.y); a3 += w2 * bfHI(q2.y);
            a4 += w2 * bfLO(q2.z); a5 += w2 * bfHI(q2.z);
            a6 += w2 * bfLO(q2.w); a7 += w2 * bfHI(q2.w);
            a0 += w3 * bfLO(q3.x); a1 += w3 * bfHI(q3.x);
            a2 += w3 * bfLO(q3.y); a3 += w3 * bfHI(q3.y);
            a4 += w3 * bfLO(q3.z); a5 += w3 * bfHI(q3.z);
            a6 += w3 * bfLO(q3.w); a7 += w3 * bfHI(q3.w);
            a0 += w4 * bfLO(q4.x); a1 += w4 * bfHI(q4.x);
            a2 += w4 * bfLO(q4.y); a3 += w4 * bfHI(q4.y);
            a4 += w4 * bfLO(q4.z); a5 += w4 * bfHI(q4.z);
            a6 += w4 * bfLO(q4.w); a7 += w4 * bfHI(q4.w);
            a0 += w5 * bfLO(q5.x); a1 += w5 * bfHI(q5.x);
            a2 += w5 * bfLO(q5.y); a3 += w5 * bfHI(q5.y);
            a4 += w5 * bfLO(q5.z); a5 += w5 * bfHI(q5.z);
            a6 += w5 * bfLO(q5.w); a7 += w5 * bfHI(q5.w);
            a0 += w6 * bfLO(q6.x); a1 += w6 * bfHI(q6.x);
            a2 += w6 * bfLO(q6.y); a3 += w6 * bfHI(q6.y);
            a4 += w6 * bfLO(q6.z); a5 += w6 * bfHI(q6.z);
            a6 += w6 * bfLO(q6.w); a7 += w6 * bfHI(q6.w);
            a0 += w7 * bfLO(q7.x); a1 += w7 * bfHI(q7.x);
            a2 += w7 * bfLO(q7.y); a3 += w7 * bfHI(q7.y);
            a4 += w7 * bfLO(q7.z); a5 += w7 * bfHI(q7.z);
            a6 += w7 * bfLO(q7.w); a7 += w7 * bfHI(q7.w);
            mA = mA2; mB = mB2; j = jn;
        }
    }

    if (LAST) {
        size_t base = (size_t)gid * DFEAT + (size_t)l * 8;
        float4 xa = *(const float4*)&x[base];
        float4 xc = *(const float4*)&x[base + 4];
        float r0 = (1.0f - ALPHA) * a0 + ALPHA * xa.x;
        float r1 = (1.0f - ALPHA) * a1 + ALPHA * xa.y;
        float r2 = (1.0f - ALPHA) * a2 + ALPHA * xa.z;
        float r3 = (1.0f - ALPHA) * a3 + ALPHA * xa.w;
        float r4 = (1.0f - ALPHA) * a4 + ALPHA * xc.x;
        float r5 = (1.0f - ALPHA) * a5 + ALPHA * xc.y;
        float r6 = (1.0f - ALPHA) * a6 + ALPHA * xc.z;
        float r7 = (1.0f - ALPHA) * a7 + ALPHA * xc.w;
        float* o = (float*)hdst;
        *(float4*)&o[base]     = make_float4(r0, r1, r2, r3);
        *(float4*)&o[base + 4] = make_float4(r4, r5, r6, r7);
    } else {
        u32x4 t = ((const u32x4*)xb)[(size_t)gid * 8 + l];
        float r0 = (1.0f - ALPHA) * a0 + ALPHA * bfLO(t.x);
        float r1 = (1.0f - ALPHA) * a1 + ALPHA * bfHI(t.x);
        float r2 = (1.0f - ALPHA) * a2 + ALPHA * bfLO(t.y);
        float r3 = (1.0f - ALPHA) * a3 + ALPHA * bfHI(t.y);
        float r4 = (1.0f - ALPHA) * a4 + ALPHA * bfLO(t.z);
        float r5 = (1.0f - ALPHA) * a5 + ALPHA * bfHI(t.z);
        float r6 = (1.0f - ALPHA) * a6 + ALPHA * bfLO(t.w);
        float r7 = (1.0f - ALPHA) * a7 + ALPHA * bfHI(t.w);
        u32x4 o;
        o.x = (f2bf(r1) << 16) | f2bf(r0);
        o.y = (f2bf(r3) << 16) | f2bf(r2);
        o.z = (f2bf(r5) << 16) | f2bf(r4);
        o.w = (f2bf(r7) << 16) | f2bf(r6);
        ((u32x4*)hdst)[(size_t)gid * 8 + l] = o;
    }
}

extern "C" void kernel_launch(void* const* d_in, const int* in_sizes, int n_in,
                              void* d_out, int out_size, void* d_ws, size_t ws_size,
                              hipStream_t stream) {
    const float* x  = (const float*)d_in[0];
    const int*   ei = (const int*)d_in[1];
    const int N = in_sizes[0] / DFEAT;   // 100000 (< 2^17, fits packed src)
    const int E = in_sizes[1] / 2;
    const int* row = ei;       // sources
    const int* col = ei + E;   // destinations

    const int NBUCK = (N + ((1 << BSHIFT) - 1)) >> BSHIFT;   // 391 (<= MAXBUCK)

    char* ws = (char*)d_ws;
    auto align256 = [](size_t v) { return (v + 255) & ~(size_t)255; };
    size_t off = 0;
    int* dpad = (int*)(ws + off);       off += align256((size_t)N * 4);
    float* dinv = (float*)(ws + off);   off += align256((size_t)N * 4);
    int* offs = (int*)(ws + off);       off += align256((size_t)N * 4);
    int* bsum = (int*)(ws + off);       off += align256((size_t)4096);
    int* btotal = (int*)(ws + off);     off += align256((size_t)MAXBUCK * 4);
    int* bstart = (int*)(ws + off);     off += align256((size_t)MAXBUCK * 4);
    int* blockhist = (int*)(ws + off);  off += align256((size_t)GR_A * MAXBUCK * 4);
    u32* bucketed = (u32*)(ws + off);   off += align256((size_t)E * 4);
    size_t metaCap = (size_t)E + (size_t)(PAD - 1) * N + 32;  // +32 prefetch slack
    u32* meta = (u32*)(ws + off);       off += align256(metaCap * 4);
    u32* xb = (u32*)(ws + off);         off += align256((size_t)N * 32 * 4);  // bf16 rows
    u32* hA = (u32*)(ws + off);         off += align256((size_t)N * 32 * 4);
    u32* hB = (u32*)(ws + off);         off += align256((size_t)N * 32 * 4);

    float* out = (float*)d_out;

    const int BLK = 256;
    const int nb    = (N + SCAN_TILE - 1) / SCAN_TILE;
    const int n8    = N * DFEAT / 8;
    const int gridC = (n8 + BLK - 1) / BLK;
    const int gridProp = (N * 8 + BLK - 1) / BLK;   // 8 threads per node
    const int chunkA = (E + GR_A - 1) / GR_A;

    hipMemsetAsync(meta, 0, metaCap * 4, stream);   // pads -> src=0, w=0
    k_hA_cvt<<<GR_A + gridC, BLK, 0, stream>>>(col, blockhist, E, NBUCK, chunkA,
                                               x, xb, n8);
    k_colsum<<<NBUCK, GR_A, 0, stream>>>(blockhist, btotal);
    k_bscan <<<1, MAXBUCK, 0, stream>>>(btotal, bstart, NBUCK);
    k_hB    <<<GR_A, BLK, 0, stream>>>(row, col, blockhist, bstart, bucketed,
                                       E, NBUCK, chunkA);
    k_degB  <<<NBUCK, BLK, 0, stream>>>(bucketed, bstart, btotal, dinv, dpad, N);
    k_scan1 <<<nb, SCAN_T, 0, stream>>>(dpad, offs, bsum, N);
    k_scan3 <<<nb, SCAN_T, 0, stream>>>(offs, bsum, N);
    k_fillB <<<NBUCK, BLK, 0, stream>>>(bucketed, bstart, btotal, offs, dinv, meta, N);

    // k=0: xb -> hA; then ping-pong; k=9 (LAST): -> out in fp32
    u32* bufs[2] = { hA, hB };
    for (int k = 0; k < KSTEPS; ++k) {
        const u32* src = (k == 0) ? xb : bufs[(k + 1) & 1];
        if (k < KSTEPS - 1) {
            k_prop<false><<<gridProp, BLK, 0, stream>>>(offs, dpad, meta, src, x, xb,
                                                        (void*)bufs[k & 1], N);
        } else {
            k_prop<true><<<gridProp, BLK, 0, stream>>>(offs, dpad, meta, src, x, xb,
                                                       (void*)out, N);
        }
    }
    (void)ws_size; (void)n_in; (void)out_size;
}

// Round 13
// 334.605 us; speedup vs baseline: 1.0216x; 1.0216x over previous
//
#include <hip/hip_runtime.h>

constexpr int DFEAT  = 64;
constexpr int KSTEPS = 10;
constexpr float ALPHA = 0.1f;
constexpr int PAD    = 8;       // CSR row length padded to multiple of 8
constexpr int BSHIFT = 8;       // 256 nodes per dst bucket
constexpr int MAXBUCK = 512;    // max buckets (N <= 131072)
constexpr int GR_A   = 128;     // bucketing blocks
constexpr int SRCSHIFT = 14;    // src-range = 16384 nodes (~2MB bf16 window)
constexpr int MAXSRCR = 16;     // max src ranges (N <= 131072 -> <= 8 at shift 14)
constexpr int RSTRIDE = 17;     // LDS row stride (bank spread)

constexpr int SCAN_T    = 256;
constexpr int SCAN_I    = 4;
constexpr int SCAN_TILE = SCAN_T * SCAN_I;  // 1024

typedef unsigned int u32;
typedef __attribute__((ext_vector_type(4))) unsigned int u32x4;

// bf16 pack helper (round-to-nearest-even), returns low 16 bits
__device__ inline u32 f2bf(float f) {
    u32 u = __float_as_uint(f);
    return ((u + 0x7fffu + ((u >> 16) & 1u)) >> 16) & 0xFFFFu;
}
__device__ inline float bfLO(u32 v) { return __uint_as_float(v << 16); }
__device__ inline float bfHI(u32 v) { return __uint_as_float(v & 0xFFFF0000u); }

// ---- A1 (fused): blocks [0,GR_A): LDS bucket histogram; rest: x->bf16 cvt ----
__global__ void __launch_bounds__(256) k_hA_cvt(
    const int* __restrict__ col, int* __restrict__ blockhist,
    int E, int nb, int chunk,
    const float* __restrict__ x, u32* __restrict__ xb, int n8) {
    __shared__ int hist[MAXBUCK];
    int t = threadIdx.x;
    if ((int)blockIdx.x < GR_A) {
        int e0 = blockIdx.x * chunk;
        int e1 = min(E, e0 + chunk);
        for (int b = t; b < MAXBUCK; b += 256) hist[b] = 0;
        __syncthreads();
        for (int e = e0 + t; e < e1; e += 256)
            atomicAdd(&hist[col[e] >> BSHIFT], 1);
        __syncthreads();
        for (int b = t; b < nb; b += 256)
            blockhist[blockIdx.x * MAXBUCK + b] = hist[b];
    } else {
        int stride = (gridDim.x - GR_A) * blockDim.x;
        const float4* x4 = (const float4*)x;
        u32x4* o4 = (u32x4*)xb;
        for (int i = (blockIdx.x - GR_A) * blockDim.x + t; i < n8; i += stride) {
            float4 a = x4[2 * i], b = x4[2 * i + 1];
            u32x4 o;
            o.x = (f2bf(a.y) << 16) | f2bf(a.x);
            o.y = (f2bf(a.w) << 16) | f2bf(a.z);
            o.z = (f2bf(b.y) << 16) | f2bf(b.x);
            o.w = (f2bf(b.w) << 16) | f2bf(b.z);
            o4[i] = o;
        }
    }
}

// ---- A2: per bucket, exclusive scan over the GR_A per-block counts ----
__global__ void k_colsum(int* __restrict__ blockhist, int* __restrict__ btotal) {
    __shared__ int s[GR_A];
    int b = blockIdx.x, t = threadIdx.x;     // GR_A threads
    int v = blockhist[t * MAXBUCK + b];
    s[t] = v;
    __syncthreads();
    for (int o = 1; o < GR_A; o <<= 1) {
        int u = (t >= o) ? s[t - o] : 0;
        __syncthreads();
        s[t] += u;
        __syncthreads();
    }
    blockhist[t * MAXBUCK + b] = s[t] - v;   // exclusive
    if (t == GR_A - 1) btotal[b] = s[t];
}

// ---- A3: exclusive scan of bucket totals -> bstart ----
__global__ void k_bscan(const int* __restrict__ btotal, int* __restrict__ bstart,
                        int nb) {
    __shared__ int s[MAXBUCK];
    int t = threadIdx.x;
    if (t < nb) s[t] = btotal[t];
    __syncthreads();
    if (t == 0) {
        int acc = 0;
        for (int i = 0; i < nb; ++i) { int v = s[i]; s[i] = acc; acc += v; }
    }
    __syncthreads();
    if (t < nb) bstart[t] = s[t];
}

// ---- A4: write edges into pre-reserved bucket segments (LDS cursors only) ----
__global__ void __launch_bounds__(256) k_hB(
    const int* __restrict__ row, const int* __restrict__ col,
    const int* __restrict__ blockhist, const int* __restrict__ bstart,
    u32* __restrict__ bucketed, int E, int nb, int chunk) {
    __shared__ int cur[MAXBUCK];
    int t  = threadIdx.x;
    int e0 = blockIdx.x * chunk;
    int e1 = min(E, e0 + chunk);
    for (int b = t; b < nb; b += 256)
        cur[b] = bstart[b] + blockhist[blockIdx.x * MAXBUCK + b];
    __syncthreads();
    for (int e = e0 + t; e < e1; e += 256) {
        int c = col[e], r = row[e];
        int rank = atomicAdd(&cur[c >> BSHIFT], 1);
        bucketed[rank] = ((u32)r << BSHIFT) | (u32)(c & ((1 << BSHIFT) - 1));
    }
}

// ---- A5: per-bucket degree count from bucketed; emit dinv + dpad ----
__global__ void __launch_bounds__(256) k_degB(
    const u32* __restrict__ bucketed, const int* __restrict__ bstart,
    const int* __restrict__ btotal, float* __restrict__ dinv,
    int* __restrict__ dpad, int N) {
    __shared__ int cnt[256];
    int b = blockIdx.x, t = threadIdx.x;
    cnt[t] = 0;
    __syncthreads();
    int p0 = bstart[b], p1 = p0 + btotal[b];
    for (int p = p0 + t; p < p1; p += 256)
        atomicAdd(&cnt[bucketed[p] & 255u], 1);
    __syncthreads();
    int node = (b << BSHIFT) + t;
    if (node < N) {
        int d = cnt[t];
        dinv[node] = (d > 0) ? rsqrtf((float)d) : 0.0f;
        dpad[node] = (d + (PAD - 1)) & ~(PAD - 1);
    }
}

// ---- scan phase 1 (exclusive scan of dpad) ----
__global__ void k_scan1(const int* __restrict__ in, int* __restrict__ out,
                        int* __restrict__ bsum, int n) {
    __shared__ int s[SCAN_T];
    int tid  = threadIdx.x;
    int base = blockIdx.x * SCAN_TILE + tid * SCAN_I;
    int v[SCAN_I];
    int sum = 0;
#pragma unroll
    for (int j = 0; j < SCAN_I; ++j) {
        v[j] = (base + j < n) ? in[base + j] : 0;
        sum += v[j];
    }
    s[tid] = sum;
    __syncthreads();
    for (int ofs = 1; ofs < SCAN_T; ofs <<= 1) {
        int t = (tid >= ofs) ? s[tid - ofs] : 0;
        __syncthreads();
        s[tid] += t;
        __syncthreads();
    }
    int excl = (tid == 0) ? 0 : s[tid - 1];
    if (tid == SCAN_T - 1) bsum[blockIdx.x] = s[tid];
#pragma unroll
    for (int j = 0; j < SCAN_I; ++j) {
        if (base + j < n) out[base + j] = excl;
        excl += v[j];
    }
}

// ---- scan phase 3: offs += prefix of bsum (scan2 inlined per block) ----
__global__ void k_scan3(int* __restrict__ offs, const int* __restrict__ bsum, int n) {
    __shared__ int s_add;
    if (threadIdx.x == 0) {
        int acc = 0;
        for (int i = 0; i < (int)blockIdx.x; ++i) acc += bsum[i];
        s_add = acc;
    }
    __syncthreads();
    int add  = s_add;
    int base = blockIdx.x * SCAN_TILE + threadIdx.x * SCAN_I;
#pragma unroll
    for (int j = 0; j < SCAN_I; ++j) {
        int i = base + j;
        if (i < n) offs[i] += add;
    }
}

// ---- pass B: per-bucket CSR fill, src-range-ordered via LDS COUNTING SORT ----
// 2 passes over the bucket's edges (count, then scatter) regardless of the
// number of src ranges. Thread t owns local node t's cursor row lc[t][*].
__global__ void __launch_bounds__(256) k_fillB(
    const u32* __restrict__ bucketed, const int* __restrict__ bstart,
    const int* __restrict__ btotal, const int* __restrict__ offs,
    const float* __restrict__ dinv, u32* __restrict__ meta, int N) {
    __shared__ int   lc[256 * RSTRIDE];
    __shared__ float ldinv[256];
    int b = blockIdx.x, t = threadIdx.x;
    int node = (b << BSHIFT) + t;
    ldinv[t] = (node < N) ? dinv[node] : 0.0f;
    for (int s = t; s < 256 * RSTRIDE; s += 256) lc[s] = 0;
    __syncthreads();
    int p0 = bstart[b], p1 = p0 + btotal[b];
    int nsrcr = (N + (1 << SRCSHIFT) - 1) >> SRCSHIFT;
    // pass 1: count per (local node, src range)
    for (int p = p0 + t; p < p1; p += 256) {
        u32 v  = bucketed[p];
        int r  = (int)(v >> BSHIFT);
        int cl = (int)(v & 255u);
        atomicAdd(&lc[cl * RSTRIDE + (r >> SRCSHIFT)], 1);
    }
    __syncthreads();
    // convert counts -> cursors (thread t owns node t); seed at offs[node]
    {
        int acc = (node < N) ? offs[node] : 0;
        for (int s = 0; s < nsrcr; ++s) {
            int c = lc[t * RSTRIDE + s];
            lc[t * RSTRIDE + s] = acc;
            acc += c;
        }
    }
    __syncthreads();
    // pass 2: scatter, ordered by src range within each row
    for (int p = p0 + t; p < p1; p += 256) {
        u32 v  = bucketed[p];
        int r  = (int)(v >> BSHIFT);
        int cl = (int)(v & 255u);
        int pos = atomicAdd(&lc[cl * RSTRIDE + (r >> SRCSHIFT)], 1);
        float w = dinv[r] * ldinv[cl];            // in [0,1]
        u32 wq = (u32)__float2int_rn(w * 32768.0f);
        if (wq > 32767u) wq = 32767u;
        meta[pos] = (wq << 17) | (u32)r;
    }
}

// ---- propagate: one 8-lane group per dst node; lane l covers features l*8..l*8+7.
// PAD=8 rows -> uniform 8-deep MLP loop, double-buffered meta, no tail.
template<bool LAST>
__global__ void __launch_bounds__(256) k_prop(
    const int* __restrict__ offs, const int* __restrict__ dpad,
    const u32* __restrict__ meta, const u32* __restrict__ hsrc,
    const float* __restrict__ x, const u32* __restrict__ xb,
    void* __restrict__ hdst, int N) {
    int gid = (int)((blockIdx.x * blockDim.x + threadIdx.x) >> 3);  // node id
    int l   = threadIdx.x & 7;                                      // lane in group
    if (gid >= N) return;
    int j   = offs[gid];
    int end = j + dpad[gid];          // multiple of 8 (or 0)

    const u32x4* h4 = (const u32x4*)hsrc;   // row r = h4[r*8 .. r*8+7]
    float a0 = 0.f, a1 = 0.f, a2 = 0.f, a3 = 0.f,
          a4 = 0.f, a5 = 0.f, a6 = 0.f, a7 = 0.f;

    if (j < end) {
        u32x4 mA = *(const u32x4*)&meta[j];
        u32x4 mB = *(const u32x4*)&meta[j + 4];
        while (j < end) {
            int jn = j + 8;
            // 8 independent gathers in flight
            u32x4 q0 = h4[(size_t)(mA.x & 0x1FFFFu) * 8 + l];
            u32x4 q1 = h4[(size_t)(mA.y & 0x1FFFFu) * 8 + l];
            u32x4 q2 = h4[(size_t)(mA.z & 0x1FFFFu) * 8 + l];
            u32x4 q3 = h4[(size_t)(mA.w & 0x1FFFFu) * 8 + l];
            u32x4 q4 = h4[(size_t)(mB.x & 0x1FFFFu) * 8 + l];
            u32x4 q5 = h4[(size_t)(mB.y & 0x1FFFFu) * 8 + l];
            u32x4 q6 = h4[(size_t)(mB.z & 0x1FFFFu) * 8 + l];
            u32x4 q7 = h4[(size_t)(mB.w & 0x1FFFFu) * 8 + l];
            // prefetch next meta (slack-allocated past array end)
            u32x4 mA2 = *(const u32x4*)&meta[jn];
            u32x4 mB2 = *(const u32x4*)&meta[jn + 4];
            float w0 = (float)(mA.x >> 17) * (1.0f / 32768.0f);
            float w1 = (float)(mA.y >> 17) * (1.0f / 32768.0f);
            float w2 = (float)(mA.z >> 17) * (1.0f / 32768.0f);
            float w3 = (float)(mA.w >> 17) * (1.0f / 32768.0f);
            float w4 = (float)(mB.x >> 17) * (1.0f / 32768.0f);
            float w5 = (float)(mB.y >> 17) * (1.0f / 32768.0f);
            float w6 = (float)(mB.z >> 17) * (1.0f / 32768.0f);
            float w7 = (float)(mB.w >> 17) * (1.0f / 32768.0f);
            a0 += w0 * bfLO(q0.x); a1 += w0 * bfHI(q0.x);
            a2 += w0 * bfLO(q0.y); a3 += w0 * bfHI(q0.y);
            a4 += w0 * bfLO(q0.z); a5 += w0 * bfHI(q0.z);
            a6 += w0 * bfLO(q0.w); a7 += w0 * bfHI(q0.w);
            a0 += w1 * bfLO(q1.x); a1 += w1 * bfHI(q1.x);
            a2 += w1 * bfLO(q1.y); a3 += w1 * bfHI(q1.y);
            a4 += w1 * bfLO(q1.z); a5 += w1 * bfHI(q1.z);
            a6 += w1 * bfLO(q1.w); a7 += w1 * bfHI(q1.w);
            a0 += w2 * bfLO(q2.x); a1 += w2 * bfHI(q2.x);
            a2 += w2 * bfLO(q2.y); a3 += w2 * bfHI(q2.y);
            a4 += w2 * bfLO(q2.z); a5 += w2 * bfHI(q2.z);
            a6 += w2 * bfLO(q2.w); a7 += w2 * bfHI(q2.w);
            a0 += w3 * bfLO(q3.x); a1 += w3 * bfHI(q3.x);
            a2 += w3 * bfLO(q3.y); a3 += w3 * bfHI(q3.y);
            a4 += w3 * bfLO(q3.z); a5 += w3 * bfHI(q3.z);
            a6 += w3 * bfLO(q3.w); a7 += w3 * bfHI(q3.w);
            a0 += w4 * bfLO(q4.x); a1 += w4 * bfHI(q4.x);
            a2 += w4 * bfLO(q4.y); a3 += w4 * bfHI(q4.y);
            a4 += w4 * bfLO(q4.z); a5 += w4 * bfHI(q4.z);
            a6 += w4 * bfLO(q4.w); a7 += w4 * bfHI(q4.w);
            a0 += w5 * bfLO(q5.x); a1 += w5 * bfHI(q5.x);
            a2 += w5 * bfLO(q5.y); a3 += w5 * bfHI(q5.y);
            a4 += w5 * bfLO(q5.z); a5 += w5 * bfHI(q5.z);
            a6 += w5 * bfLO(q5.w); a7 += w5 * bfHI(q5.w);
            a0 += w6 * bfLO(q6.x); a1 += w6 * bfHI(q6.x);
            a2 += w6 * bfLO(q6.y); a3 += w6 * bfHI(q6.y);
            a4 += w6 * bfLO(q6.z); a5 += w6 * bfHI(q6.z);
            a6 += w6 * bfLO(q6.w); a7 += w6 * bfHI(q6.w);
            a0 += w7 * bfLO(q7.x); a1 += w7 * bfHI(q7.x);
            a2 += w7 * bfLO(q7.y); a3 += w7 * bfHI(q7.y);
            a4 += w7 * bfLO(q7.z); a5 += w7 * bfHI(q7.z);
            a6 += w7 * bfLO(q7.w); a7 += w7 * bfHI(q7.w);
            mA = mA2; mB = mB2; j = jn;
        }
    }

    if (LAST) {
        size_t base = (size_t)gid * DFEAT + (size_t)l * 8;
        float4 xa = *(const float4*)&x[base];
        float4 xc = *(const float4*)&x[base + 4];
        float r0 = (1.0f - ALPHA) * a0 + ALPHA * xa.x;
        float r1 = (1.0f - ALPHA) * a1 + ALPHA * xa.y;
        float r2 = (1.0f - ALPHA) * a2 + ALPHA * xa.z;
        float r3 = (1.0f - ALPHA) * a3 + ALPHA * xa.w;
        float r4 = (1.0f - ALPHA) * a4 + ALPHA * xc.x;
        float r5 = (1.0f - ALPHA) * a5 + ALPHA * xc.y;
        float r6 = (1.0f - ALPHA) * a6 + ALPHA * xc.z;
        float r7 = (1.0f - ALPHA) * a7 + ALPHA * xc.w;
        float* o = (float*)hdst;
        *(float4*)&o[base]     = make_float4(r0, r1, r2, r3);
        *(float4*)&o[base + 4] = make_float4(r4, r5, r6, r7);
    } else {
        u32x4 t = ((const u32x4*)xb)[(size_t)gid * 8 + l];
        float r0 = (1.0f - ALPHA) * a0 + ALPHA * bfLO(t.x);
        float r1 = (1.0f - ALPHA) * a1 + ALPHA * bfHI(t.x);
        float r2 = (1.0f - ALPHA) * a2 + ALPHA * bfLO(t.y);
        float r3 = (1.0f - ALPHA) * a3 + ALPHA * bfHI(t.y);
        float r4 = (1.0f - ALPHA) * a4 + ALPHA * bfLO(t.z);
        float r5 = (1.0f - ALPHA) * a5 + ALPHA * bfHI(t.z);
        float r6 = (1.0f - ALPHA) * a6 + ALPHA * bfLO(t.w);
        float r7 = (1.0f - ALPHA) * a7 + ALPHA * bfHI(t.w);
        u32x4 o;
        o.x = (f2bf(r1) << 16) | f2bf(r0);
        o.y = (f2bf(r3) << 16) | f2bf(r2);
        o.z = (f2bf(r5) << 16) | f2bf(r4);
        o.w = (f2bf(r7) << 16) | f2bf(r6);
        ((u32x4*)hdst)[(size_t)gid * 8 + l] = o;
    }
}

extern "C" void kernel_launch(void* const* d_in, const int* in_sizes, int n_in,
                              void* d_out, int out_size, void* d_ws, size_t ws_size,
                              hipStream_t stream) {
    const float* x  = (const float*)d_in[0];
    const int*   ei = (const int*)d_in[1];
    const int N = in_sizes[0] / DFEAT;   // 100000 (< 2^17, fits packed src)
    const int E = in_sizes[1] / 2;
    const int* row = ei;       // sources
    const int* col = ei + E;   // destinations

    const int NBUCK = (N + ((1 << BSHIFT) - 1)) >> BSHIFT;   // 391 (<= MAXBUCK)

    char* ws = (char*)d_ws;
    auto align256 = [](size_t v) { return (v + 255) & ~(size_t)255; };
    size_t off = 0;
    int* dpad = (int*)(ws + off);       off += align256((size_t)N * 4);
    float* dinv = (float*)(ws + off);   off += align256((size_t)N * 4);
    int* offs = (int*)(ws + off);       off += align256((size_t)N * 4);
    int* bsum = (int*)(ws + off);       off += align256((size_t)4096);
    int* btotal = (int*)(ws + off);     off += align256((size_t)MAXBUCK * 4);
    int* bstart = (int*)(ws + off);     off += align256((size_t)MAXBUCK * 4);
    int* blockhist = (int*)(ws + off);  off += align256((size_t)GR_A * MAXBUCK * 4);
    u32* bucketed = (u32*)(ws + off);   off += align256((size_t)E * 4);
    size_t metaCap = (size_t)E + (size_t)(PAD - 1) * N + 32;  // +32 prefetch slack
    u32* meta = (u32*)(ws + off);       off += align256(metaCap * 4);
    u32* xb = (u32*)(ws + off);         off += align256((size_t)N * 32 * 4);  // bf16 rows
    u32* hA = (u32*)(ws + off);         off += align256((size_t)N * 32 * 4);
    u32* hB = (u32*)(ws + off);         off += align256((size_t)N * 32 * 4);

    float* out = (float*)d_out;

    const int BLK = 256;
    const int nb    = (N + SCAN_TILE - 1) / SCAN_TILE;
    const int n8    = N * DFEAT / 8;
    const int gridC = (n8 + BLK - 1) / BLK;
    const int gridProp = (N * 8 + BLK - 1) / BLK;   // 8 threads per node
    const int chunkA = (E + GR_A - 1) / GR_A;

    hipMemsetAsync(meta, 0, metaCap * 4, stream);   // pads -> src=0, w=0
    k_hA_cvt<<<GR_A + gridC, BLK, 0, stream>>>(col, blockhist, E, NBUCK, chunkA,
                                               x, xb, n8);
    k_colsum<<<NBUCK, GR_A, 0, stream>>>(blockhist, btotal);
    k_bscan <<<1, MAXBUCK, 0, stream>>>(btotal, bstart, NBUCK);
    k_hB    <<<GR_A, BLK, 0, stream>>>(row, col, blockhist, bstart, bucketed,
                                       E, NBUCK, chunkA);
    k_degB  <<<NBUCK, BLK, 0, stream>>>(bucketed, bstart, btotal, dinv, dpad, N);
    k_scan1 <<<nb, SCAN_T, 0, stream>>>(dpad, offs, bsum, N);
    k_scan3 <<<nb, SCAN_T, 0, stream>>>(offs, bsum, N);
    k_fillB <<<NBUCK, BLK, 0, stream>>>(bucketed, bstart, btotal, offs, dinv, meta, N);

    // k=0: xb -> hA; then ping-pong; k=9 (LAST): -> out in fp32
    u32* bufs[2] = { hA, hB };
    for (int k = 0; k < KSTEPS; ++k) {
        const u32* src = (k == 0) ? xb : bufs[(k + 1) & 1];
        if (k < KSTEPS - 1) {
            k_prop<false><<<gridProp, BLK, 0, stream>>>(offs, dpad, meta, src, x, xb,
                                                        (void*)bufs[k & 1], N);
        } else {
            k_prop<true><<<gridProp, BLK, 0, stream>>>(offs, dpad, meta, src, x, xb,
                                                       (void*)out, N);
        }
    }
    (void)ws_size; (void)n_in; (void)out_size;
}